// Round 9
// baseline (2512.148 us; speedup 1.0000x reference)
//
#include <hip/hip_runtime.h>
#include <math.h>

typedef __bf16 bf16_t;
typedef float f32x4 __attribute__((ext_vector_type(4)));
typedef __bf16 bf16x8 __attribute__((ext_vector_type(8)));

union FragU { uint4 u; bf16x8 b; };

#define MFMA_BF16(a, b, c) __builtin_amdgcn_mfma_f32_16x16x32_bf16((a), (b), (c), 0, 0, 0)

__device__ __forceinline__ void glds16(const void* g, void* l) {
  __builtin_amdgcn_global_load_lds((const __attribute__((address_space(1))) void*)g,
                                   (__attribute__((address_space(3))) void*)l, 16, 0, 0);
}

// ------------------------------------------------------------------ rope tables (fp32)
__global__ void rope_k(const int* __restrict__ pos_ids, float* __restrict__ cosb,
                       float* __restrict__ sinb) {
  int s = blockIdx.x;
  int d = threadIdx.x;            // 0..63
  int pair = d >> 5, j = d & 31;
  float p = (float)pos_ids[s * 2 + pair];
  float inv = powf(10000.f, -(float)j / 32.f);
  float v = p * inv;
  float c = cosf(v), sn = sinf(v);
  cosb[s * 128 + d] = c;  cosb[s * 128 + d + 64] = c;
  sinb[s * 128 + d] = sn; sinb[s * 128 + d + 64] = sn;
}

// ------------------------------------------------------------------ rmsnorm fp32 -> bf16
__global__ __launch_bounds__(256) void rmsnorm_bf_k(const float* __restrict__ in,
                                                    const float* __restrict__ w,
                                                    bf16_t* __restrict__ out, int cols) {
  int row = blockIdx.x;
  const float* x = in + (size_t)row * cols;
  float ss = 0.f;
  for (int c = threadIdx.x; c < cols; c += 256) { float v = x[c]; ss = fmaf(v, v, ss); }
#pragma unroll
  for (int o = 32; o; o >>= 1) ss += __shfl_xor(ss, o);
  __shared__ float red[4];
  if ((threadIdx.x & 63) == 0) red[threadIdx.x >> 6] = ss;
  __syncthreads();
  float tot = red[0] + red[1] + red[2] + red[3];
  float rs = rsqrtf(tot / (float)cols + 1e-6f);
  bf16_t* y = out + (size_t)row * cols;
  for (int c = threadIdx.x; c < cols; c += 256) y[c] = (bf16_t)(x[c] * rs * w[c]);
}

// ------------------------------------------------------------------ transpose+convert: in (K,N) f32 -> out (N,Kpad) bf16, zero-pad k>=K
__global__ __launch_bounds__(256) void transpose_cvt_k(const float* __restrict__ in,
                                                       bf16_t* __restrict__ out,
                                                       int K, int N, int Kpad) {
  __shared__ float t[32][33];
  int k0 = blockIdx.x * 32, n0 = blockIdx.y * 32;
  int tx = threadIdx.x & 31, ty = threadIdx.x >> 5;  // 8 rows
#pragma unroll
  for (int i = 0; i < 4; ++i) {
    int k = k0 + ty + 8 * i;
    t[ty + 8 * i][tx] = (k < K) ? in[(size_t)k * N + n0 + tx] : 0.f;
  }
  __syncthreads();
#pragma unroll
  for (int i = 0; i < 4; ++i) {
    int n = n0 + ty + 8 * i;
    out[(size_t)n * Kpad + k0 + tx] = (bf16_t)t[tx][ty + 8 * i];
  }
}

// ------------------------------------------------------------------ straight convert with K-pad: in (R,K) f32 -> out (R,Kpad) bf16
__global__ void convert_pad_k(const float* __restrict__ in, bf16_t* __restrict__ out,
                              int R, int K, int Kpad) {
  int idx = blockIdx.x * 256 + threadIdx.x;
  if (idx < R * Kpad) {
    int r = idx / Kpad, k = idx - r * Kpad;
    out[idx] = (k < K) ? (bf16_t)in[(size_t)r * K + k] : (bf16_t)0.f;
  }
}

// ------------------------------------------------------------------ qk rmsnorm + rope: qkv bf16 -> q_bf (scaled, [h][s][d]), k_bf
__global__ __launch_bounds__(128) void qknorm_rope_k(const bf16_t* __restrict__ qkv,
    const float* __restrict__ qn, const float* __restrict__ kn,
    const float* __restrict__ cosb, const float* __restrict__ sinb,
    bf16_t* __restrict__ qo, bf16_t* __restrict__ ko) {
  const int s = blockIdx.x / 12, h = blockIdx.x % 12;
  const int d = threadIdx.x;  // 0..127
  __shared__ float nrm[128];
  __shared__ float red[2];
  const float cs = cosb[s * 128 + d], sn = sinb[s * 128 + d];
  const float QS = 0.08838834764831845f * 1.4426950408889634f;  // D^-0.5 * log2(e)
#pragma unroll
  for (int part = 0; part < 2; ++part) {
    const bf16_t* p = qkv + (size_t)s * 4608 + part * 1536 + h * 128;
    float v = (float)p[d];
    float ss = v * v;
#pragma unroll
    for (int o = 32; o; o >>= 1) ss += __shfl_xor(ss, o);
    if ((d & 63) == 0) red[d >> 6] = ss;
    __syncthreads();
    float rs = rsqrtf((red[0] + red[1]) * (1.f / 128.f) + 1e-6f);
    float nv = v * rs * (part ? kn[d] : qn[d]);
    nrm[d] = nv;
    __syncthreads();
    float rot = (d < 64) ? -nrm[d + 64] : nrm[d - 64];
    float val = nv * cs + rot * sn;
    bf16_t* dst = part ? ko : qo;
    dst[((size_t)h * 1600 + s) * 128 + d] = (bf16_t)(part ? val : val * QS);
    __syncthreads();
  }
}

// ------------------------------------------------------------------ v transpose: qkv bf16 [s][2C + h*128 + d] -> vt [h][d][s]
__global__ __launch_bounds__(256) void vtrans_k(const bf16_t* __restrict__ qkv,
                                                bf16_t* __restrict__ vt) {
  __shared__ __align__(16) bf16_t t[128][136];
  const int h = blockIdx.x, s0 = blockIdx.y * 128;
  const int tx = threadIdx.x & 15, ty = threadIdx.x >> 4;
#pragma unroll
  for (int i = 0; i < 8; ++i) {
    int sl = ty + 16 * i, s = s0 + sl;
    uint4 v = {0u, 0u, 0u, 0u};
    if (s < 1600) v = *(const uint4*)&qkv[(size_t)s * 4608 + 3072 + h * 128 + tx * 8];
    *(uint4*)&t[sl][tx * 8] = v;
  }
  __syncthreads();
  if (s0 + tx * 8 < 1600) {
#pragma unroll
    for (int i = 0; i < 8; ++i) {
      int dd = ty + 16 * i;
      bf16_t tmp[8];
#pragma unroll
      for (int j = 0; j < 8; ++j) tmp[j] = t[tx * 8 + j][dd];
      *(uint4*)&vt[(size_t)(h * 128 + dd) * 1600 + s0 + tx * 8] = *(uint4*)tmp;
    }
  }
}

// ------------------------------------------------------------------ split-KV flash attention, fixed-max softmax, XCD-clustered blocks.
// score*log2e <= sqrt(128)*log2e = 16.33 (|q|=|k|=sqrt(128) after rmsnorm,
// rope norm-preserving) -> p = exp2(s-16), no running max.
// Block swizzle: swz = (bid&7)*150 + (bid>>3) clusters each head's blocks
// onto one XCD so its 819KB K/V stays L2-resident (2 heads < 4MB L2).
__global__ __launch_bounds__(256) void attn_mfma(const bf16_t* __restrict__ qg,
    const bf16_t* __restrict__ kg, const bf16_t* __restrict__ vg,
    bf16_t* __restrict__ o) {
  const int bid = blockIdx.x;
  const int swz = (bid & 7) * 150 + (bid >> 3);   // bijective on [0,1200)
  const int h = swz / 100;
  const int q0 = (swz % 100) * 16;
  const int tid = threadIdx.x;
  const int w = tid >> 6, lane = tid & 63;
  const int fq = lane >> 4, fr = lane & 15;
  const bf16_t* qh = qg + (size_t)h * 1600 * 128;
  const bf16_t* kh = kg + (size_t)h * 1600 * 128;
  const bf16_t* vh = vg + (size_t)h * 128 * 1600;
  __shared__ __align__(16) bf16_t pl[4][512];   // per-wave P tile [cb4][q16][8]
  __shared__ float O_l[4][16][132];             // per-wave partial O (padded)
  __shared__ float l_l[4][16];
  FragU aq[4];
#pragma unroll
  for (int db = 0; db < 4; ++db)
    aq[db].u = *(const uint4*)&qh[(size_t)(q0 + fr) * 128 + db * 32 + fq * 8];
  f32x4 zero = {0.f, 0.f, 0.f, 0.f};
  f32x4 oacc[8];
#pragma unroll
  for (int nb = 0; nb < 8; ++nb) oacc[nb] = zero;
  float lrun[4] = {0.f, 0.f, 0.f, 0.f};
  const int kb0 = ((50 * w) >> 2) * 32;
  const int kb1 = ((50 * (w + 1)) >> 2) * 32;
  for (int kb = kb0; kb < kb1; kb += 32) {
    f32x4 s0 = zero, s1 = zero;
#pragma unroll
    for (int db = 0; db < 4; ++db) {
      FragU bk0, bk1;
      bk0.u = *(const uint4*)&kh[(size_t)(kb + fr) * 128 + db * 32 + fq * 8];
      bk1.u = *(const uint4*)&kh[(size_t)(kb + 16 + fr) * 128 + db * 32 + fq * 8];
      s0 = MFMA_BF16(aq[db].b, bk0.b, s0);
      s1 = MFMA_BF16(aq[db].b, bk1.b, s1);
    }
    float p0[4], p1[4];
#pragma unroll
    for (int r = 0; r < 4; ++r) {
      p0[r] = exp2f(s0[r] - 16.f);
      p1[r] = exp2f(s1[r] - 16.f);
      lrun[r] += p0[r] + p1[r];
    }
#pragma unroll
    for (int r = 0; r < 4; ++r) {
      int q = fq * 4 + r;
      int kk0 = fr;
      pl[w][((kk0 >> 3) * 16 + q) * 8 + (kk0 & 7)] = (bf16_t)p0[r];
      int kk1 = 16 + fr;
      pl[w][((kk1 >> 3) * 16 + q) * 8 + (kk1 & 7)] = (bf16_t)p1[r];
    }
    FragU ap;
    ap.u = *(const uint4*)&pl[w][(fq * 16 + fr) * 8];
#pragma unroll
    for (int nb = 0; nb < 8; ++nb) {
      FragU bv;
      bv.u = *(const uint4*)&vh[(size_t)(nb * 16 + fr) * 1600 + kb + fq * 8];
      oacc[nb] = MFMA_BF16(ap.b, bv.b, oacc[nb]);
    }
  }
  // one-time row-sum reduce across the 16 fr lanes
#pragma unroll
  for (int r = 0; r < 4; ++r) {
    lrun[r] += __shfl_xor(lrun[r], 1);
    lrun[r] += __shfl_xor(lrun[r], 2);
    lrun[r] += __shfl_xor(lrun[r], 4);
    lrun[r] += __shfl_xor(lrun[r], 8);
  }
  if (fr == 0) {
#pragma unroll
    for (int r = 0; r < 4; ++r) l_l[w][fq * 4 + r] = lrun[r];
  }
#pragma unroll
  for (int nb = 0; nb < 8; ++nb)
#pragma unroll
    for (int r = 0; r < 4; ++r)
      O_l[w][fq * 4 + r][nb * 16 + fr] = oacc[nb][r];
  __syncthreads();
  // combine (all partials share the same fixed max -> plain sums)
  {
    const int q = tid >> 4, d0 = (tid & 15) * 8;
    float lsum = l_l[0][q] + l_l[1][q] + l_l[2][q] + l_l[3][q];
    float inv = 1.f / lsum;
    bf16_t tmp[8];
#pragma unroll
    for (int j = 0; j < 8; ++j) {
      float acc = O_l[0][q][d0 + j] + O_l[1][q][d0 + j] +
                  O_l[2][q][d0 + j] + O_l[3][q][d0 + j];
      tmp[j] = (bf16_t)(acc * inv);
    }
    *(uint4*)&o[(size_t)(q0 + q) * 1536 + h * 128 + d0] = *(uint4*)tmp;
  }
}

// ------------------------------------------------------------------ silu(gate)*up in place on fused buffer [1600][8192]
__global__ void silu_mul_k(bf16_t* __restrict__ gu) {
  int i = blockIdx.x * 256 + threadIdx.x;   // over 1600*1024 quads
  if (i < 1600 * 1024) {
    int m = i >> 10, j = (i & 1023) * 4;
    size_t base = (size_t)m * 8192 + j;
    union U { uint2 v; bf16_t b[4]; };
    U gv, uv, ov;
    gv.v = *(const uint2*)&gu[base];
    uv.v = *(const uint2*)&gu[base + 4096];
#pragma unroll
    for (int jj = 0; jj < 4; ++jj) {
      float x = (float)gv.b[jj], y = (float)uv.b[jj];
      ov.b[jj] = (bf16_t)(x / (1.f + __expf(-x)) * y);
    }
    *(uint2*)&gu[base] = ov.v;
  }
}

// ------------------------------------------------------------------ gather for conv-as-GEMM (bf16)
__global__ void gather_conv_k(const bf16_t* __restrict__ hf, bf16_t* __restrict__ abuf) {
  int idx = blockIdx.x * 256 + threadIdx.x;  // 400*6144
  if (idx < 400 * 6144) {
    int n = idx / 6144, k = idx - n * 6144;
    abuf[idx] = hf[(size_t)(4 * n + (k & 3)) * 1536 + (k >> 2)];
  }
}

// ------------------------------------------------------------------ 64x64-tile bf16 MFMA GEMM, double-buffered
template <int ACT, int BIAS, int RES, int OBF>
__global__ __launch_bounds__(256) void gemm64(const bf16_t* __restrict__ A,
    const bf16_t* __restrict__ Bt, const float* __restrict__ bias,
    const float* __restrict__ res, float* __restrict__ outf,
    bf16_t* __restrict__ outb, int M, int N, int K, int lda) {
  __shared__ __align__(16) bf16_t As[2][2048];  // [buf][cb4][row64][8]
  __shared__ __align__(16) bf16_t Bs[2][2048];
  const int tid = threadIdx.x;
  const int lane = tid & 63, w = tid >> 6;
  const int m0 = blockIdx.y * 64, n0 = blockIdx.x * 64;
  const int fq = lane >> 4, fr = lane & 15;
  const int wc = w * 16;
  const bf16_t* ag = A + (size_t)(m0 + lane) * lda + w * 8;
  const bf16_t* bg = Bt + (size_t)(n0 + lane) * K + w * 8;
  f32x4 zero = {0.f, 0.f, 0.f, 0.f};
  f32x4 acc[4];
#pragma unroll
  for (int m = 0; m < 4; ++m) acc[m] = zero;
  const int nt = K >> 5;
  glds16(ag, &As[0][w * 512]);
  glds16(bg, &Bs[0][w * 512]);
  ag += 32; bg += 32;
  asm volatile("s_waitcnt vmcnt(0)" ::: "memory");
  __builtin_amdgcn_s_barrier();
  for (int t = 0; t < nt; ++t) {
    const int cur = t & 1;
    if (t + 1 < nt) {
      glds16(ag, &As[cur ^ 1][w * 512]);
      glds16(bg, &Bs[cur ^ 1][w * 512]);
      ag += 32; bg += 32;
    }
    FragU bw, af[4];
    bw.u = *(const uint4*)&Bs[cur][(fq * 64 + wc + fr) * 8];
#pragma unroll
    for (int m = 0; m < 4; ++m)
      af[m].u = *(const uint4*)&As[cur][(fq * 64 + m * 16 + fr) * 8];
#pragma unroll
    for (int m = 0; m < 4; ++m)
      acc[m] = MFMA_BF16(af[m].b, bw.b, acc[m]);
    asm volatile("s_waitcnt vmcnt(0)" ::: "memory");
    __builtin_amdgcn_s_barrier();
  }
#pragma unroll
  for (int m = 0; m < 4; ++m) {
#pragma unroll
    for (int r = 0; r < 4; ++r) {
      int gm = m0 + m * 16 + fq * 4 + r;
      if (gm < M) {
        int gn = n0 + wc + fr;
        float v = acc[m][r];
        if (BIAS) v += bias[gn];
        if (ACT == 1) {
          float x = v;
          float t = 0.7978845608028654f * fmaf(0.044715f * x, x * x, x);
          float e = exp2f(t * 2.8853900817779268f);   // exp(2t)
          v = x * e / (e + 1.f);                       // 0.5x(1+tanh t)
        }
        if (RES) v += res[(size_t)gm * N + gn];
        if (OBF) outb[(size_t)gm * N + gn] = (bf16_t)v;
        else outf[(size_t)gm * N + gn] = v;
      }
    }
  }
}

// ------------------------------------------------------------------ 128x128-tile bf16 MFMA GEMM, double-buffered (AI=64)
template <int ACT, int BIAS, int RES, int OBF>
__global__ __launch_bounds__(256) void gemm128(const bf16_t* __restrict__ A,
    const bf16_t* __restrict__ Bt, const float* __restrict__ bias,
    const float* __restrict__ res, float* __restrict__ outf,
    bf16_t* __restrict__ outb, int M, int N, int K, int lda) {
  __shared__ __align__(16) bf16_t As[2][4096];  // [buf][cb4][row128][8]
  __shared__ __align__(16) bf16_t Bs[2][4096];
  const int tid = threadIdx.x;
  const int lane = tid & 63, w = tid >> 6;
  const int m0 = blockIdx.y * 128, n0 = blockIdx.x * 128;
  const int wr = (w >> 1) * 64, wc = (w & 1) * 64;
  const int fq = lane >> 4, fr = lane & 15;
  const int u1 = w * 64 + lane, u2 = u1 + 256;
  const int r1 = u1 & 127, c1 = u1 >> 7;
  const int r2 = u2 & 127, c2 = u2 >> 7;
  const bf16_t* a1 = A + (size_t)(m0 + r1) * lda + c1 * 8;
  const bf16_t* a2 = A + (size_t)(m0 + r2) * lda + c2 * 8;
  const bf16_t* b1 = Bt + (size_t)(n0 + r1) * K + c1 * 8;
  const bf16_t* b2 = Bt + (size_t)(n0 + r2) * K + c2 * 8;
  f32x4 zero = {0.f, 0.f, 0.f, 0.f};
  f32x4 acc[4][4];
#pragma unroll
  for (int m = 0; m < 4; ++m)
#pragma unroll
    for (int n = 0; n < 4; ++n) acc[m][n] = zero;
  const int nt = K >> 5;
  glds16(a1, &As[0][w * 512]); glds16(a2, &As[0][2048 + w * 512]);
  glds16(b1, &Bs[0][w * 512]); glds16(b2, &Bs[0][2048 + w * 512]);
  a1 += 32; a2 += 32; b1 += 32; b2 += 32;
  asm volatile("s_waitcnt vmcnt(0)" ::: "memory");
  __builtin_amdgcn_s_barrier();
  for (int t = 0; t < nt; ++t) {
    const int cur = t & 1;
    if (t + 1 < nt) {
      glds16(a1, &As[cur ^ 1][w * 512]); glds16(a2, &As[cur ^ 1][2048 + w * 512]);
      glds16(b1, &Bs[cur ^ 1][w * 512]); glds16(b2, &Bs[cur ^ 1][2048 + w * 512]);
      a1 += 32; a2 += 32; b1 += 32; b2 += 32;
    }
    FragU af[4], bw[4];
#pragma unroll
    for (int m = 0; m < 4; ++m)
      af[m].u = *(const uint4*)&As[cur][(fq * 128 + wr + m * 16 + fr) * 8];
#pragma unroll
    for (int n = 0; n < 4; ++n)
      bw[n].u = *(const uint4*)&Bs[cur][(fq * 128 + wc + n * 16 + fr) * 8];
#pragma unroll
    for (int m = 0; m < 4; ++m)
#pragma unroll
      for (int n = 0; n < 4; ++n)
        acc[m][n] = MFMA_BF16(af[m].b, bw[n].b, acc[m][n]);
    asm volatile("s_waitcnt vmcnt(0)" ::: "memory");
    __builtin_amdgcn_s_barrier();
  }
#pragma unroll
  for (int m = 0; m < 4; ++m) {
#pragma unroll
    for (int r = 0; r < 4; ++r) {
      int gm = m0 + wr + m * 16 + fq * 4 + r;
      if (gm < M) {
#pragma unroll
        for (int n = 0; n < 4; ++n) {
          int gn = n0 + wc + n * 16 + fr;
          float v = acc[m][n][r];
          if (BIAS) v += bias[gn];
          if (ACT == 1) {
            float x = v;
            float t2 = 0.7978845608028654f * fmaf(0.044715f * x, x * x, x);
            float e = exp2f(t2 * 2.8853900817779268f);
            v = x * e / (e + 1.f);
          }
          if (RES) v += res[(size_t)gm * N + gn];
          if (OBF) outb[(size_t)gm * N + gn] = (bf16_t)v;
          else outf[(size_t)gm * N + gn] = v;
        }
      }
    }
  }
}

// ------------------------------------------------------------------ launch
extern "C" void kernel_launch(void* const* d_in, const int* in_sizes, int n_in,
                              void* d_out, int out_size, void* d_ws, size_t ws_size,
                              hipStream_t stream) {
  (void)in_sizes; (void)n_in; (void)out_size; (void)ws_size;
  const float* pixel     = (const float*)d_in[0];
  const int*   pos_ids   = (const int*)d_in[1];
  const float* w_patch   = (const float*)d_in[3];
  const float* qkv_w     = (const float*)d_in[4];
  const float* qkv_b     = (const float*)d_in[5];
  const float* q_norm_w  = (const float*)d_in[6];
  const float* k_norm_w  = (const float*)d_in[7];
  const float* proj_w    = (const float*)d_in[8];
  const float* proj_b    = (const float*)d_in[9];
  const float* norm1_w   = (const float*)d_in[10];
  const float* norm2_w   = (const float*)d_in[11];
  const float* gate_w    = (const float*)d_in[12];
  const float* up_w      = (const float*)d_in[13];
  const float* down_w    = (const float*)d_in[14];
  const float* post_ln_w = (const float*)d_in[15];
  const float* conv_w    = (const float*)d_in[16];
  const float* conv_b    = (const float*)d_in[17];
  const float* fc1_w     = (const float*)d_in[18];
  const float* fc1_b     = (const float*)d_in[19];
  const float* fc2_w     = (const float*)d_in[20];
  const float* fc2_b     = (const float*)d_in[21];
  float* out = (float*)d_out;

  char* wsb = (char*)d_ws;
  float*  h     = (float*)(wsb + 0);            // 9,830,400 B
  bf16_t* xo    = (bf16_t*)(wsb + 9830400);     // 4,915,200 B (x / o shared)
  char*   R1    = wsb + 14745600;               // 29,491,200 B multi-use
  bf16_t* qkvb  = (bf16_t*)(R1);
  bf16_t* qb    = (bf16_t*)(R1 + 14745600);
  bf16_t* kb    = (bf16_t*)(R1 + 19660800);
  bf16_t* vb    = (bf16_t*)(R1 + 24576000);
  bf16_t* gub   = (bf16_t*)(R1);                // 26,214,400 B fused gate|up
  bf16_t* pixb  = (bf16_t*)(R1);
  bf16_t* ab    = (bf16_t*)(R1);
  bf16_t* dbuf  = (bf16_t*)(R1 + 4915200);
  bf16_t* ebuf  = (bf16_t*)(R1 + 6144000);
  float*  cosb  = (float*)(wsb + 44236800);     // 819,200 B
  float*  sinb  = (float*)(wsb + 45056000);     // 819,200 B
  char*   W     = wsb + 45875200;               // 56,623,104 B (per-layer bf16 weights)
  bf16_t* qkvwT = (bf16_t*)(W);
  bf16_t* projT = (bf16_t*)(W + 14155776);
  bf16_t* gateupT = (bf16_t*)(W + 18874368);    // (8192,1536) = gate(4096)|up(4096)
  bf16_t* upT   = (bf16_t*)(W + 31457280);
  bf16_t* downT = (bf16_t*)(W + 44040192);
  bf16_t* convB = (bf16_t*)(W);
  bf16_t* fc1T  = (bf16_t*)(W + 18874368);
  bf16_t* fc2T  = (bf16_t*)(W + 37748736);
  bf16_t* wpT   = (bf16_t*)(wsb + 102498304);   // 3,637,248 B

  rope_k<<<1600, 64, 0, stream>>>(pos_ids, cosb, sinb);
  convert_pad_k<<<(1600 * 1184 + 255) / 256, 256, 0, stream>>>(pixel, pixb, 1600, 1176, 1184);
  transpose_cvt_k<<<dim3(37, 48), 256, 0, stream>>>(w_patch, wpT, 1176, 1536, 1184);
  gemm64<0, 0, 0, 0><<<dim3(24, 25), 256, 0, stream>>>(
      pixb, wpT, nullptr, nullptr, h, nullptr, 1600, 1536, 1184, 1184);

  for (int l = 0; l < 4; ++l) {
    const float* qw = qkv_w  + (size_t)l * 1536 * 4608;
    const float* pw = proj_w + (size_t)l * 1536 * 1536;
    const float* gw = gate_w + (size_t)l * 1536 * 4096;
    const float* uw = up_w   + (size_t)l * 1536 * 4096;
    const float* dw = down_w + (size_t)l * 4096 * 1536;
    transpose_cvt_k<<<dim3(48, 144), 256, 0, stream>>>(qw, qkvwT, 1536, 4608, 1536);
    transpose_cvt_k<<<dim3(48, 48),  256, 0, stream>>>(pw, projT, 1536, 1536, 1536);
    transpose_cvt_k<<<dim3(48, 128), 256, 0, stream>>>(gw, gateupT, 1536, 4096, 1536);
    transpose_cvt_k<<<dim3(48, 128), 256, 0, stream>>>(uw, upT,   1536, 4096, 1536);
    transpose_cvt_k<<<dim3(128, 48), 256, 0, stream>>>(dw, downT, 4096, 1536, 4096);

    rmsnorm_bf_k<<<1600, 256, 0, stream>>>(h, norm1_w + (size_t)l * 1536, xo, 1536);
    gemm128<0, 1, 0, 1><<<dim3(36, 13), 256, 0, stream>>>(
        xo, qkvwT, qkv_b + (size_t)l * 4608, nullptr, nullptr, qkvb, 1600, 4608, 1536, 1536);
    qknorm_rope_k<<<1600 * 12, 128, 0, stream>>>(
        qkvb, q_norm_w + (size_t)l * 128, k_norm_w + (size_t)l * 128, cosb, sinb, qb, kb);
    vtrans_k<<<dim3(12, 13), 256, 0, stream>>>(qkvb, vb);
    attn_mfma<<<1200, 256, 0, stream>>>(qb, kb, vb, xo);
    gemm64<0, 1, 1, 0><<<dim3(24, 25), 256, 0, stream>>>(
        xo, projT, proj_b + (size_t)l * 1536, h, h, nullptr, 1600, 1536, 1536, 1536);
    rmsnorm_bf_k<<<1600, 256, 0, stream>>>(h, norm2_w + (size_t)l * 1536, xo, 1536);
    gemm128<0, 0, 0, 1><<<dim3(64, 13), 256, 0, stream>>>(
        xo, gateupT, nullptr, nullptr, nullptr, gub, 1600, 8192, 1536, 1536);
    silu_mul_k<<<6400, 256, 0, stream>>>(gub);
    gemm64<0, 0, 1, 0><<<dim3(24, 25), 256, 0, stream>>>(
        gub, downT, nullptr, h, h, nullptr, 1600, 1536, 4096, 8192);
  }

  // head
  convert_pad_k<<<(1536 * 6144 + 255) / 256, 256, 0, stream>>>(conv_w, convB, 1536, 6144, 6144);
  transpose_cvt_k<<<dim3(48, 192), 256, 0, stream>>>(fc1_w, fc1T, 1536, 6144, 1536);
  transpose_cvt_k<<<dim3(192, 48), 256, 0, stream>>>(fc2_w, fc2T, 6144, 1536, 6144);
  rmsnorm_bf_k<<<1600, 256, 0, stream>>>(h, post_ln_w, xo, 1536);
  gather_conv_k<<<(400 * 6144 + 255) / 256, 256, 0, stream>>>(xo, ab);
  gemm64<0, 1, 0, 1><<<dim3(24, 7), 256, 0, stream>>>(
      ab, convB, conv_b, nullptr, nullptr, dbuf, 400, 1536, 6144, 6144);
  gemm64<1, 1, 0, 1><<<dim3(96, 7), 256, 0, stream>>>(
      dbuf, fc1T, fc1_b, nullptr, nullptr, ebuf, 400, 6144, 1536, 1536);
  gemm64<0, 1, 0, 0><<<dim3(24, 7), 256, 0, stream>>>(
      ebuf, fc2T, fc2_b, nullptr, out, nullptr, 400, 1536, 6144, 6144);
}

// Round 10
// 2292.859 us; speedup vs baseline: 1.0956x; 1.0956x over previous
//
#include <hip/hip_runtime.h>
#include <math.h>

typedef __bf16 bf16_t;
typedef float f32x4 __attribute__((ext_vector_type(4)));
typedef __bf16 bf16x8 __attribute__((ext_vector_type(8)));

union FragU { uint4 u; bf16x8 b; };

#define MFMA_BF16(a, b, c) __builtin_amdgcn_mfma_f32_16x16x32_bf16((a), (b), (c), 0, 0, 0)

__device__ __forceinline__ void glds16(const void* g, void* l) {
  __builtin_amdgcn_global_load_lds((const __attribute__((address_space(1))) void*)g,
                                   (__attribute__((address_space(3))) void*)l, 16, 0, 0);
}

// ------------------------------------------------------------------ rope tables (fp32)
__global__ void rope_k(const int* __restrict__ pos_ids, float* __restrict__ cosb,
                       float* __restrict__ sinb) {
  int s = blockIdx.x;
  int d = threadIdx.x;            // 0..63
  int pair = d >> 5, j = d & 31;
  float p = (float)pos_ids[s * 2 + pair];
  float inv = powf(10000.f, -(float)j / 32.f);
  float v = p * inv;
  float c = cosf(v), sn = sinf(v);
  cosb[s * 128 + d] = c;  cosb[s * 128 + d + 64] = c;
  sinb[s * 128 + d] = sn; sinb[s * 128 + d + 64] = sn;
}

// ------------------------------------------------------------------ rmsnorm fp32 -> bf16
__global__ __launch_bounds__(256) void rmsnorm_bf_k(const float* __restrict__ in,
                                                    const float* __restrict__ w,
                                                    bf16_t* __restrict__ out, int cols) {
  int row = blockIdx.x;
  const float* x = in + (size_t)row * cols;
  float ss = 0.f;
  for (int c = threadIdx.x; c < cols; c += 256) { float v = x[c]; ss = fmaf(v, v, ss); }
#pragma unroll
  for (int o = 32; o; o >>= 1) ss += __shfl_xor(ss, o);
  __shared__ float red[4];
  if ((threadIdx.x & 63) == 0) red[threadIdx.x >> 6] = ss;
  __syncthreads();
  float tot = red[0] + red[1] + red[2] + red[3];
  float rs = rsqrtf(tot / (float)cols + 1e-6f);
  bf16_t* y = out + (size_t)row * cols;
  for (int c = threadIdx.x; c < cols; c += 256) y[c] = (bf16_t)(x[c] * rs * w[c]);
}

// ------------------------------------------------------------------ transpose+convert: in (K,N) f32 -> out (N,Kpad) bf16, zero-pad k>=K
__global__ __launch_bounds__(256) void transpose_cvt_k(const float* __restrict__ in,
                                                       bf16_t* __restrict__ out,
                                                       int K, int N, int Kpad) {
  __shared__ float t[32][33];
  int k0 = blockIdx.x * 32, n0 = blockIdx.y * 32;
  int tx = threadIdx.x & 31, ty = threadIdx.x >> 5;  // 8 rows
#pragma unroll
  for (int i = 0; i < 4; ++i) {
    int k = k0 + ty + 8 * i;
    t[ty + 8 * i][tx] = (k < K) ? in[(size_t)k * N + n0 + tx] : 0.f;
  }
  __syncthreads();
#pragma unroll
  for (int i = 0; i < 4; ++i) {
    int n = n0 + ty + 8 * i;
    out[(size_t)n * Kpad + k0 + tx] = (bf16_t)t[tx][ty + 8 * i];
  }
}

// ------------------------------------------------------------------ straight convert with K-pad: in (R,K) f32 -> out (R,Kpad) bf16
__global__ void convert_pad_k(const float* __restrict__ in, bf16_t* __restrict__ out,
                              int R, int K, int Kpad) {
  int idx = blockIdx.x * 256 + threadIdx.x;
  if (idx < R * Kpad) {
    int r = idx / Kpad, k = idx - r * Kpad;
    out[idx] = (k < K) ? (bf16_t)in[(size_t)r * K + k] : (bf16_t)0.f;
  }
}

// ------------------------------------------------------------------ qk rmsnorm + rope: qkv bf16 -> q_bf (scaled, [h][s][d]), k_bf
__global__ __launch_bounds__(128) void qknorm_rope_k(const bf16_t* __restrict__ qkv,
    const float* __restrict__ qn, const float* __restrict__ kn,
    const float* __restrict__ cosb, const float* __restrict__ sinb,
    bf16_t* __restrict__ qo, bf16_t* __restrict__ ko) {
  const int s = blockIdx.x / 12, h = blockIdx.x % 12;
  const int d = threadIdx.x;  // 0..127
  __shared__ float nrm[128];
  __shared__ float red[2];
  const float cs = cosb[s * 128 + d], sn = sinb[s * 128 + d];
  const float QS = 0.08838834764831845f * 1.4426950408889634f;  // D^-0.5 * log2(e)
#pragma unroll
  for (int part = 0; part < 2; ++part) {
    const bf16_t* p = qkv + (size_t)s * 4608 + part * 1536 + h * 128;
    float v = (float)p[d];
    float ss = v * v;
#pragma unroll
    for (int o = 32; o; o >>= 1) ss += __shfl_xor(ss, o);
    if ((d & 63) == 0) red[d >> 6] = ss;
    __syncthreads();
    float rs = rsqrtf((red[0] + red[1]) * (1.f / 128.f) + 1e-6f);
    float nv = v * rs * (part ? kn[d] : qn[d]);
    nrm[d] = nv;
    __syncthreads();
    float rot = (d < 64) ? -nrm[d + 64] : nrm[d - 64];
    float val = nv * cs + rot * sn;
    bf16_t* dst = part ? ko : qo;
    dst[((size_t)h * 1600 + s) * 128 + d] = (bf16_t)(part ? val : val * QS);
    __syncthreads();
  }
}

// ------------------------------------------------------------------ v transpose: qkv bf16 [s][2C + h*128 + d] -> vt [h][d][s]
__global__ __launch_bounds__(256) void vtrans_k(const bf16_t* __restrict__ qkv,
                                                bf16_t* __restrict__ vt) {
  __shared__ __align__(16) bf16_t t[128][136];
  const int h = blockIdx.x, s0 = blockIdx.y * 128;
  const int tx = threadIdx.x & 15, ty = threadIdx.x >> 4;
#pragma unroll
  for (int i = 0; i < 8; ++i) {
    int sl = ty + 16 * i, s = s0 + sl;
    uint4 v = {0u, 0u, 0u, 0u};
    if (s < 1600) v = *(const uint4*)&qkv[(size_t)s * 4608 + 3072 + h * 128 + tx * 8];
    *(uint4*)&t[sl][tx * 8] = v;
  }
  __syncthreads();
  if (s0 + tx * 8 < 1600) {
#pragma unroll
    for (int i = 0; i < 8; ++i) {
      int dd = ty + 16 * i;
      bf16_t tmp[8];
#pragma unroll
      for (int j = 0; j < 8; ++j) tmp[j] = t[tx * 8 + j][dd];
      *(uint4*)&vt[(size_t)(h * 128 + dd) * 1600 + s0 + tx * 8] = *(uint4*)tmp;
    }
  }
}

// ------------------------------------------------------------------ flash attention, LDS-staged K/V (GEMM-style 2-phase dbuf).
// 2 waves/block, 32 q-rows/block, 32-key tiles. Fixed-max softmax:
// score*log2e <= sqrt(128)*log2e = 16.33 -> p = exp2(s-16), no running max.
// q: [h][s][d] (pre-scaled by D^-0.5*log2e), k: [h][s][d], v: [h][d][s], o: [s][C]
__global__ __launch_bounds__(128) void attn_mfma(const bf16_t* __restrict__ qg,
    const bf16_t* __restrict__ kg, const bf16_t* __restrict__ vg,
    bf16_t* __restrict__ o) {
  const int bid = blockIdx.x;
  const int swz = (bid & 7) * 75 + (bid >> 3);   // 600 = 8*75, bijective
  const int h = swz / 50;
  const int q0 = (swz % 50) * 32;
  const int tid = threadIdx.x;       // 0..127
  const int w = tid >> 6, lane = tid & 63;
  const int fq = lane >> 4, fr = lane & 15;
  const bf16_t* qh = qg + (size_t)h * 1600 * 128;
  const bf16_t* kh = kg + (size_t)h * 1600 * 128;
  const bf16_t* vh = vg + (size_t)h * 128 * 1600;
  __shared__ __align__(16) bf16_t Ks[2][4096];   // [cb16][key32][8]  8KB/buf
  __shared__ __align__(16) bf16_t Vs[2][4096];   // [cb4][d128][8]    8KB/buf
  __shared__ __align__(16) bf16_t pl[2][512];    // per-wave P [cb4][q16][8]
  // staging offsets: 4 chunks per thread per tile; chunk j = c*128 + w*64 + lane
  int off_k[4], off_v[4], ldsb[4];
#pragma unroll
  for (int c = 0; c < 4; ++c) {
    int j = c * 128 + w * 64 + lane;
    off_k[c] = (j & 31) * 128 + (j >> 5) * 8;       // key*128 + cb*8
    off_v[c] = (j & 127) * 1600 + (j >> 7) * 8;     // d*1600 + cb*8
    ldsb[c] = (c * 128 + w * 64) * 8;               // wave-uniform elem base
  }
  // q fragments in registers
  FragU aq[4];
#pragma unroll
  for (int db = 0; db < 4; ++db)
    aq[db].u = *(const uint4*)&qh[(size_t)(q0 + w * 16 + fr) * 128 + db * 32 + fq * 8];
  f32x4 zero = {0.f, 0.f, 0.f, 0.f};
  f32x4 oacc[8];
#pragma unroll
  for (int nb = 0; nb < 8; ++nb) oacc[nb] = zero;
  float lrun[4] = {0.f, 0.f, 0.f, 0.f};
  // prologue: stage tile 0 into buf 0
#pragma unroll
  for (int c = 0; c < 4; ++c) {
    glds16(kh + off_k[c], &Ks[0][ldsb[c]]);
    glds16(vh + off_v[c], &Vs[0][ldsb[c]]);
  }
  asm volatile("s_waitcnt vmcnt(0)" ::: "memory");
  __builtin_amdgcn_s_barrier();
  for (int t = 0; t < 50; ++t) {
    const int cur = t & 1;
    if (t + 1 < 50) {
      const int kb = (t + 1) * 32;
#pragma unroll
      for (int c = 0; c < 4; ++c) {
        glds16(kh + (size_t)kb * 128 + off_k[c], &Ks[cur ^ 1][ldsb[c]]);
        glds16(vh + kb + off_v[c], &Vs[cur ^ 1][ldsb[c]]);
      }
    }
    // QK^T from LDS
    f32x4 s0 = zero, s1 = zero;
#pragma unroll
    for (int db = 0; db < 4; ++db) {
      FragU bk0, bk1;
      bk0.u = *(const uint4*)&Ks[cur][((db * 4 + fq) * 32 + fr) * 8];
      bk1.u = *(const uint4*)&Ks[cur][((db * 4 + fq) * 32 + 16 + fr) * 8];
      s0 = MFMA_BF16(aq[db].b, bk0.b, s0);
      s1 = MFMA_BF16(aq[db].b, bk1.b, s1);
    }
    float p0[4], p1[4];
#pragma unroll
    for (int r = 0; r < 4; ++r) {
      p0[r] = exp2f(s0[r] - 16.f);
      p1[r] = exp2f(s1[r] - 16.f);
      lrun[r] += p0[r] + p1[r];
    }
#pragma unroll
    for (int r = 0; r < 4; ++r) {
      int q = fq * 4 + r;
      int kk0 = fr;
      pl[w][((kk0 >> 3) * 16 + q) * 8 + (kk0 & 7)] = (bf16_t)p0[r];
      int kk1 = 16 + fr;
      pl[w][((kk1 >> 3) * 16 + q) * 8 + (kk1 & 7)] = (bf16_t)p1[r];
    }
    FragU ap;
    ap.u = *(const uint4*)&pl[w][(fq * 16 + fr) * 8];
#pragma unroll
    for (int nb = 0; nb < 8; ++nb) {
      FragU bv;
      bv.u = *(const uint4*)&Vs[cur][(fq * 128 + nb * 16 + fr) * 8];
      oacc[nb] = MFMA_BF16(ap.b, bv.b, oacc[nb]);
    }
    asm volatile("s_waitcnt vmcnt(0)" ::: "memory");
    __builtin_amdgcn_s_barrier();
  }
  // row-sum reduce across the 16 fr lanes, then write
#pragma unroll
  for (int r = 0; r < 4; ++r) {
    lrun[r] += __shfl_xor(lrun[r], 1);
    lrun[r] += __shfl_xor(lrun[r], 2);
    lrun[r] += __shfl_xor(lrun[r], 4);
    lrun[r] += __shfl_xor(lrun[r], 8);
  }
  float inv_[4];
#pragma unroll
  for (int r = 0; r < 4; ++r) inv_[r] = 1.f / lrun[r];
#pragma unroll
  for (int nb = 0; nb < 8; ++nb)
#pragma unroll
    for (int r = 0; r < 4; ++r) {
      int qq = q0 + w * 16 + fq * 4 + r;
      o[(size_t)qq * 1536 + h * 128 + nb * 16 + fr] = (bf16_t)(oacc[nb][r] * inv_[r]);
    }
}

// ------------------------------------------------------------------ silu(gate)*up in place on fused buffer [1600][8192]
__global__ void silu_mul_k(bf16_t* __restrict__ gu) {
  int i = blockIdx.x * 256 + threadIdx.x;   // over 1600*1024 quads
  if (i < 1600 * 1024) {
    int m = i >> 10, j = (i & 1023) * 4;
    size_t base = (size_t)m * 8192 + j;
    union U { uint2 v; bf16_t b[4]; };
    U gv, uv, ov;
    gv.v = *(const uint2*)&gu[base];
    uv.v = *(const uint2*)&gu[base + 4096];
#pragma unroll
    for (int jj = 0; jj < 4; ++jj) {
      float x = (float)gv.b[jj], y = (float)uv.b[jj];
      ov.b[jj] = (bf16_t)(x / (1.f + __expf(-x)) * y);
    }
    *(uint2*)&gu[base] = ov.v;
  }
}

// ------------------------------------------------------------------ gather for conv-as-GEMM (bf16)
__global__ void gather_conv_k(const bf16_t* __restrict__ hf, bf16_t* __restrict__ abuf) {
  int idx = blockIdx.x * 256 + threadIdx.x;  // 400*6144
  if (idx < 400 * 6144) {
    int n = idx / 6144, k = idx - n * 6144;
    abuf[idx] = hf[(size_t)(4 * n + (k & 3)) * 1536 + (k >> 2)];
  }
}

// ------------------------------------------------------------------ 64x64-tile bf16 MFMA GEMM, double-buffered
template <int ACT, int BIAS, int RES, int OBF>
__global__ __launch_bounds__(256) void gemm64(const bf16_t* __restrict__ A,
    const bf16_t* __restrict__ Bt, const float* __restrict__ bias,
    const float* __restrict__ res, float* __restrict__ outf,
    bf16_t* __restrict__ outb, int M, int N, int K, int lda) {
  __shared__ __align__(16) bf16_t As[2][2048];  // [buf][cb4][row64][8]
  __shared__ __align__(16) bf16_t Bs[2][2048];
  const int tid = threadIdx.x;
  const int lane = tid & 63, w = tid >> 6;
  const int m0 = blockIdx.y * 64, n0 = blockIdx.x * 64;
  const int fq = lane >> 4, fr = lane & 15;
  const int wc = w * 16;
  const bf16_t* ag = A + (size_t)(m0 + lane) * lda + w * 8;
  const bf16_t* bg = Bt + (size_t)(n0 + lane) * K + w * 8;
  f32x4 zero = {0.f, 0.f, 0.f, 0.f};
  f32x4 acc[4];
#pragma unroll
  for (int m = 0; m < 4; ++m) acc[m] = zero;
  const int nt = K >> 5;
  glds16(ag, &As[0][w * 512]);
  glds16(bg, &Bs[0][w * 512]);
  ag += 32; bg += 32;
  asm volatile("s_waitcnt vmcnt(0)" ::: "memory");
  __builtin_amdgcn_s_barrier();
  for (int t = 0; t < nt; ++t) {
    const int cur = t & 1;
    if (t + 1 < nt) {
      glds16(ag, &As[cur ^ 1][w * 512]);
      glds16(bg, &Bs[cur ^ 1][w * 512]);
      ag += 32; bg += 32;
    }
    FragU bw, af[4];
    bw.u = *(const uint4*)&Bs[cur][(fq * 64 + wc + fr) * 8];
#pragma unroll
    for (int m = 0; m < 4; ++m)
      af[m].u = *(const uint4*)&As[cur][(fq * 64 + m * 16 + fr) * 8];
#pragma unroll
    for (int m = 0; m < 4; ++m)
      acc[m] = MFMA_BF16(af[m].b, bw.b, acc[m]);
    asm volatile("s_waitcnt vmcnt(0)" ::: "memory");
    __builtin_amdgcn_s_barrier();
  }
#pragma unroll
  for (int m = 0; m < 4; ++m) {
#pragma unroll
    for (int r = 0; r < 4; ++r) {
      int gm = m0 + m * 16 + fq * 4 + r;
      if (gm < M) {
        int gn = n0 + wc + fr;
        float v = acc[m][r];
        if (BIAS) v += bias[gn];
        if (ACT == 1) {
          float x = v;
          float t = 0.7978845608028654f * fmaf(0.044715f * x, x * x, x);
          float e = exp2f(t * 2.8853900817779268f);   // exp(2t)
          v = x * e / (e + 1.f);                       // 0.5x(1+tanh t)
        }
        if (RES) v += res[(size_t)gm * N + gn];
        if (OBF) outb[(size_t)gm * N + gn] = (bf16_t)v;
        else outf[(size_t)gm * N + gn] = v;
      }
    }
  }
}

// ------------------------------------------------------------------ 128x128-tile bf16 MFMA GEMM, double-buffered (AI=64)
template <int ACT, int BIAS, int RES, int OBF>
__global__ __launch_bounds__(256) void gemm128(const bf16_t* __restrict__ A,
    const bf16_t* __restrict__ Bt, const float* __restrict__ bias,
    const float* __restrict__ res, float* __restrict__ outf,
    bf16_t* __restrict__ outb, int M, int N, int K, int lda) {
  __shared__ __align__(16) bf16_t As[2][4096];  // [buf][cb4][row128][8]
  __shared__ __align__(16) bf16_t Bs[2][4096];
  const int tid = threadIdx.x;
  const int lane = tid & 63, w = tid >> 6;
  const int m0 = blockIdx.y * 128, n0 = blockIdx.x * 128;
  const int wr = (w >> 1) * 64, wc = (w & 1) * 64;
  const int fq = lane >> 4, fr = lane & 15;
  const int u1 = w * 64 + lane, u2 = u1 + 256;
  const int r1 = u1 & 127, c1 = u1 >> 7;
  const int r2 = u2 & 127, c2 = u2 >> 7;
  const bf16_t* a1 = A + (size_t)(m0 + r1) * lda + c1 * 8;
  const bf16_t* a2 = A + (size_t)(m0 + r2) * lda + c2 * 8;
  const bf16_t* b1 = Bt + (size_t)(n0 + r1) * K + c1 * 8;
  const bf16_t* b2 = Bt + (size_t)(n0 + r2) * K + c2 * 8;
  f32x4 zero = {0.f, 0.f, 0.f, 0.f};
  f32x4 acc[4][4];
#pragma unroll
  for (int m = 0; m < 4; ++m)
#pragma unroll
    for (int n = 0; n < 4; ++n) acc[m][n] = zero;
  const int nt = K >> 5;
  glds16(a1, &As[0][w * 512]); glds16(a2, &As[0][2048 + w * 512]);
  glds16(b1, &Bs[0][w * 512]); glds16(b2, &Bs[0][2048 + w * 512]);
  a1 += 32; a2 += 32; b1 += 32; b2 += 32;
  asm volatile("s_waitcnt vmcnt(0)" ::: "memory");
  __builtin_amdgcn_s_barrier();
  for (int t = 0; t < nt; ++t) {
    const int cur = t & 1;
    if (t + 1 < nt) {
      glds16(a1, &As[cur ^ 1][w * 512]); glds16(a2, &As[cur ^ 1][2048 + w * 512]);
      glds16(b1, &Bs[cur ^ 1][w * 512]); glds16(b2, &Bs[cur ^ 1][2048 + w * 512]);
      a1 += 32; a2 += 32; b1 += 32; b2 += 32;
    }
    FragU af[4], bw[4];
#pragma unroll
    for (int m = 0; m < 4; ++m)
      af[m].u = *(const uint4*)&As[cur][(fq * 128 + wr + m * 16 + fr) * 8];
#pragma unroll
    for (int n = 0; n < 4; ++n)
      bw[n].u = *(const uint4*)&Bs[cur][(fq * 128 + wc + n * 16 + fr) * 8];
#pragma unroll
    for (int m = 0; m < 4; ++m)
#pragma unroll
      for (int n = 0; n < 4; ++n)
        acc[m][n] = MFMA_BF16(af[m].b, bw[n].b, acc[m][n]);
    asm volatile("s_waitcnt vmcnt(0)" ::: "memory");
    __builtin_amdgcn_s_barrier();
  }
#pragma unroll
  for (int m = 0; m < 4; ++m) {
#pragma unroll
    for (int r = 0; r < 4; ++r) {
      int gm = m0 + wr + m * 16 + fq * 4 + r;
      if (gm < M) {
#pragma unroll
        for (int n = 0; n < 4; ++n) {
          int gn = n0 + wc + n * 16 + fr;
          float v = acc[m][n][r];
          if (BIAS) v += bias[gn];
          if (ACT == 1) {
            float x = v;
            float t2 = 0.7978845608028654f * fmaf(0.044715f * x, x * x, x);
            float e = exp2f(t2 * 2.8853900817779268f);
            v = x * e / (e + 1.f);
          }
          if (RES) v += res[(size_t)gm * N + gn];
          if (OBF) outb[(size_t)gm * N + gn] = (bf16_t)v;
          else outf[(size_t)gm * N + gn] = v;
        }
      }
    }
  }
}

// ------------------------------------------------------------------ launch
extern "C" void kernel_launch(void* const* d_in, const int* in_sizes, int n_in,
                              void* d_out, int out_size, void* d_ws, size_t ws_size,
                              hipStream_t stream) {
  (void)in_sizes; (void)n_in; (void)out_size; (void)ws_size;
  const float* pixel     = (const float*)d_in[0];
  const int*   pos_ids   = (const int*)d_in[1];
  const float* w_patch   = (const float*)d_in[3];
  const float* qkv_w     = (const float*)d_in[4];
  const float* qkv_b     = (const float*)d_in[5];
  const float* q_norm_w  = (const float*)d_in[6];
  const float* k_norm_w  = (const float*)d_in[7];
  const float* proj_w    = (const float*)d_in[8];
  const float* proj_b    = (const float*)d_in[9];
  const float* norm1_w   = (const float*)d_in[10];
  const float* norm2_w   = (const float*)d_in[11];
  const float* gate_w    = (const float*)d_in[12];
  const float* up_w      = (const float*)d_in[13];
  const float* down_w    = (const float*)d_in[14];
  const float* post_ln_w = (const float*)d_in[15];
  const float* conv_w    = (const float*)d_in[16];
  const float* conv_b    = (const float*)d_in[17];
  const float* fc1_w     = (const float*)d_in[18];
  const float* fc1_b     = (const float*)d_in[19];
  const float* fc2_w     = (const float*)d_in[20];
  const float* fc2_b     = (const float*)d_in[21];
  float* out = (float*)d_out;

  char* wsb = (char*)d_ws;
  float*  h     = (float*)(wsb + 0);            // 9,830,400 B
  bf16_t* xo    = (bf16_t*)(wsb + 9830400);     // 4,915,200 B (x / o shared)
  char*   R1    = wsb + 14745600;               // 29,491,200 B multi-use
  bf16_t* qkvb  = (bf16_t*)(R1);
  bf16_t* qb    = (bf16_t*)(R1 + 14745600);
  bf16_t* kb    = (bf16_t*)(R1 + 19660800);
  bf16_t* vb    = (bf16_t*)(R1 + 24576000);
  bf16_t* gub   = (bf16_t*)(R1);                // 26,214,400 B fused gate|up
  bf16_t* pixb  = (bf16_t*)(R1);
  bf16_t* ab    = (bf16_t*)(R1);
  bf16_t* dbuf  = (bf16_t*)(R1 + 4915200);
  bf16_t* ebuf  = (bf16_t*)(R1 + 6144000);
  float*  cosb  = (float*)(wsb + 44236800);     // 819,200 B
  float*  sinb  = (float*)(wsb + 45056000);     // 819,200 B
  char*   W     = wsb + 45875200;               // 56,623,104 B (per-layer bf16 weights)
  bf16_t* qkvwT = (bf16_t*)(W);
  bf16_t* projT = (bf16_t*)(W + 14155776);
  bf16_t* gateupT = (bf16_t*)(W + 18874368);    // (8192,1536) = gate(4096)|up(4096)
  bf16_t* upT   = (bf16_t*)(W + 31457280);
  bf16_t* downT = (bf16_t*)(W + 44040192);
  bf16_t* convB = (bf16_t*)(W);
  bf16_t* fc1T  = (bf16_t*)(W + 18874368);
  bf16_t* fc2T  = (bf16_t*)(W + 37748736);
  bf16_t* wpT   = (bf16_t*)(wsb + 102498304);   // 3,637,248 B

  rope_k<<<1600, 64, 0, stream>>>(pos_ids, cosb, sinb);
  convert_pad_k<<<(1600 * 1184 + 255) / 256, 256, 0, stream>>>(pixel, pixb, 1600, 1176, 1184);
  transpose_cvt_k<<<dim3(37, 48), 256, 0, stream>>>(w_patch, wpT, 1176, 1536, 1184);
  gemm64<0, 0, 0, 0><<<dim3(24, 25), 256, 0, stream>>>(
      pixb, wpT, nullptr, nullptr, h, nullptr, 1600, 1536, 1184, 1184);

  for (int l = 0; l < 4; ++l) {
    const float* qw = qkv_w  + (size_t)l * 1536 * 4608;
    const float* pw = proj_w + (size_t)l * 1536 * 1536;
    const float* gw = gate_w + (size_t)l * 1536 * 4096;
    const float* uw = up_w   + (size_t)l * 1536 * 4096;
    const float* dw = down_w + (size_t)l * 4096 * 1536;
    transpose_cvt_k<<<dim3(48, 144), 256, 0, stream>>>(qw, qkvwT, 1536, 4608, 1536);
    transpose_cvt_k<<<dim3(48, 48),  256, 0, stream>>>(pw, projT, 1536, 1536, 1536);
    transpose_cvt_k<<<dim3(48, 128), 256, 0, stream>>>(gw, gateupT, 1536, 4096, 1536);
    transpose_cvt_k<<<dim3(48, 128), 256, 0, stream>>>(uw, upT,   1536, 4096, 1536);
    transpose_cvt_k<<<dim3(128, 48), 256, 0, stream>>>(dw, downT, 4096, 1536, 4096);

    rmsnorm_bf_k<<<1600, 256, 0, stream>>>(h, norm1_w + (size_t)l * 1536, xo, 1536);
    gemm128<0, 1, 0, 1><<<dim3(36, 13), 256, 0, stream>>>(
        xo, qkvwT, qkv_b + (size_t)l * 4608, nullptr, nullptr, qkvb, 1600, 4608, 1536, 1536);
    qknorm_rope_k<<<1600 * 12, 128, 0, stream>>>(
        qkvb, q_norm_w + (size_t)l * 128, k_norm_w + (size_t)l * 128, cosb, sinb, qb, kb);
    vtrans_k<<<dim3(12, 13), 256, 0, stream>>>(qkvb, vb);
    attn_mfma<<<600, 128, 0, stream>>>(qb, kb, vb, xo);
    gemm64<0, 1, 1, 0><<<dim3(24, 25), 256, 0, stream>>>(
        xo, projT, proj_b + (size_t)l * 1536, h, h, nullptr, 1600, 1536, 1536, 1536);
    rmsnorm_bf_k<<<1600, 256, 0, stream>>>(h, norm2_w + (size_t)l * 1536, xo, 1536);
    gemm128<0, 0, 0, 1><<<dim3(64, 13), 256, 0, stream>>>(
        xo, gateupT, nullptr, nullptr, nullptr, gub, 1600, 8192, 1536, 1536);
    silu_mul_k<<<6400, 256, 0, stream>>>(gub);
    gemm64<0, 0, 1, 0><<<dim3(24, 25), 256, 0, stream>>>(
        gub, downT, nullptr, h, h, nullptr, 1600, 1536, 4096, 8192);
  }

  // head
  convert_pad_k<<<(1536 * 6144 + 255) / 256, 256, 0, stream>>>(conv_w, convB, 1536, 6144, 6144);
  transpose_cvt_k<<<dim3(48, 192), 256, 0, stream>>>(fc1_w, fc1T, 1536, 6144, 1536);
  transpose_cvt_k<<<dim3(192, 48), 256, 0, stream>>>(fc2_w, fc2T, 6144, 1536, 6144);
  rmsnorm_bf_k<<<1600, 256, 0, stream>>>(h, post_ln_w, xo, 1536);
  gather_conv_k<<<(400 * 6144 + 255) / 256, 256, 0, stream>>>(xo, ab);
  gemm64<0, 1, 0, 1><<<dim3(24, 7), 256, 0, stream>>>(
      ab, convB, conv_b, nullptr, nullptr, dbuf, 400, 1536, 6144, 6144);
  gemm64<1, 1, 0, 1><<<dim3(96, 7), 256, 0, stream>>>(
      dbuf, fc1T, fc1_b, nullptr, nullptr, ebuf, 400, 6144, 1536, 1536);
  gemm64<0, 1, 0, 0><<<dim3(24, 7), 256, 0, stream>>>(
      ebuf, fc2T, fc2_b, nullptr, out, nullptr, 400, 1536, 6144, 6144);
}